// Round 1
// baseline (5428.974 us; speedup 1.0000x reference)
//
#include <hip/hip_runtime.h>

#define D_FEAT 128

__global__ void zero_out_kernel(float* __restrict__ out, int n4) {
    int i = blockIdx.x * blockDim.x + threadIdx.x;
    if (i < n4) {
        ((float4*)out)[i] = make_float4(0.f, 0.f, 0.f, 0.f);
    }
}

// 32 lanes per edge; each lane handles one float4 (4 floats) of the 128-wide row.
__global__ void coo_scatter_kernel(const int* __restrict__ rows,
                                   const int* __restrict__ cols,
                                   const float* __restrict__ vals,
                                   const float* __restrict__ embeds,
                                   float* __restrict__ out,
                                   int n_edges) {
    int tid  = blockIdx.x * blockDim.x + threadIdx.x;
    int edge = tid >> 5;        // 32 threads per edge
    int lane = tid & 31;        // 0..31, each covers 4 floats
    if (edge >= n_edges) return;

    int   r = rows[edge];
    int   c = cols[edge];
    float v = vals[edge];

    const float4* src = (const float4*)(embeds + (size_t)c * D_FEAT);
    float4 e = src[lane];

    float* dst = out + (size_t)r * D_FEAT + lane * 4;
    atomicAdd(dst + 0, v * e.x);
    atomicAdd(dst + 1, v * e.y);
    atomicAdd(dst + 2, v * e.z);
    atomicAdd(dst + 3, v * e.w);
}

extern "C" void kernel_launch(void* const* d_in, const int* in_sizes, int n_in,
                              void* d_out, int out_size, void* d_ws, size_t ws_size,
                              hipStream_t stream) {
    const int*   rows   = (const int*)d_in[0];
    const int*   cols   = (const int*)d_in[1];
    const float* vals   = (const float*)d_in[2];
    const float* embeds = (const float*)d_in[3];
    float*       out    = (float*)d_out;

    const int n_edges = in_sizes[0];
    const int out_n4  = out_size / 4;   // out_size = N_NODES * D_FEAT floats

    {
        int block = 256;
        int grid  = (out_n4 + block - 1) / block;
        zero_out_kernel<<<grid, block, 0, stream>>>(out, out_n4);
    }
    {
        int block = 256;                       // 8 edges per block
        long long total = (long long)n_edges * 32;
        int grid = (int)((total + block - 1) / block);
        coo_scatter_kernel<<<grid, block, 0, stream>>>(rows, cols, vals, embeds, out, n_edges);
    }
}

// Round 2
// 912.386 us; speedup vs baseline: 5.9503x; 5.9503x over previous
//
#include <hip/hip_runtime.h>

#define D_FEAT 128
#define SCAN_THREADS 1024

// ---------- fallback path (round-1 atomic scatter) ----------
__global__ void zero_out_kernel(float* __restrict__ out, int n4) {
    int i = blockIdx.x * blockDim.x + threadIdx.x;
    if (i < n4) ((float4*)out)[i] = make_float4(0.f, 0.f, 0.f, 0.f);
}

__global__ void coo_scatter_atomic_kernel(const int* __restrict__ rows,
                                          const int* __restrict__ cols,
                                          const float* __restrict__ vals,
                                          const float* __restrict__ embeds,
                                          float* __restrict__ out,
                                          int n_edges) {
    int tid  = blockIdx.x * blockDim.x + threadIdx.x;
    int edge = tid >> 5;
    int lane = tid & 31;
    if (edge >= n_edges) return;
    int   r = rows[edge];
    int   c = cols[edge];
    float v = vals[edge];
    const float4* src = (const float4*)(embeds + (size_t)c * D_FEAT);
    float4 e = src[lane];
    float* dst = out + (size_t)r * D_FEAT + lane * 4;
    atomicAdd(dst + 0, v * e.x);
    atomicAdd(dst + 1, v * e.y);
    atomicAdd(dst + 2, v * e.z);
    atomicAdd(dst + 3, v * e.w);
}

// ---------- sorted path ----------
__global__ void hist_kernel(const int* __restrict__ rows, int* __restrict__ counts, int n) {
    int i = blockIdx.x * blockDim.x + threadIdx.x;
    if (i < n) atomicAdd(&counts[rows[i]], 1);
}

// Single-block chunked exclusive scan: counts[0..n) -> offsets[0..n], cursor copy.
__global__ void scan_kernel(const int* __restrict__ counts,
                            int* __restrict__ offsets,
                            int* __restrict__ cursor,
                            int n, int total) {
    __shared__ int s_sums[SCAN_THREADS];
    int tid = threadIdx.x;
    int chunk = (n + SCAN_THREADS - 1) / SCAN_THREADS;
    int begin = tid * chunk;
    int end   = begin + chunk; if (end > n) end = n;
    int sum = 0;
    for (int i = begin; i < end; ++i) sum += counts[i];
    s_sums[tid] = sum;
    __syncthreads();
    // Hillis-Steele inclusive scan over per-thread sums
    for (int off = 1; off < SCAN_THREADS; off <<= 1) {
        int t = (tid >= off) ? s_sums[tid - off] : 0;
        __syncthreads();
        s_sums[tid] += t;
        __syncthreads();
    }
    int run = s_sums[tid] - sum;  // exclusive prefix of this thread's chunk
    for (int i = begin; i < end; ++i) {
        offsets[i] = run;
        cursor[i]  = run;
        run += counts[i];
    }
    if (tid == 0) offsets[n] = total;
}

__global__ void scatter_pairs_kernel(const int* __restrict__ rows,
                                     const int* __restrict__ cols,
                                     const float* __restrict__ vals,
                                     int* __restrict__ cursor,
                                     int2* __restrict__ pairs,
                                     int n) {
    int i = blockIdx.x * blockDim.x + threadIdx.x;
    if (i >= n) return;
    int r = rows[i];
    int pos = atomicAdd(&cursor[r], 1);
    pairs[pos] = make_int2(cols[i], __float_as_int(vals[i]));
}

// 128 threads/block = 4 groups of 32 lanes; each group reduces one row.
// Lane l owns float4 at dims [4l, 4l+4).
__global__ void reduce_kernel(const int* __restrict__ offsets,
                              const int2* __restrict__ pairs,
                              const float* __restrict__ embeds,
                              float* __restrict__ out,
                              int n_rows) {
    int g    = threadIdx.x >> 5;
    int lane = threadIdx.x & 31;
    int row  = blockIdx.x * 4 + g;
    if (row >= n_rows) return;
    int start = offsets[row];
    int end   = offsets[row + 1];
    float4 acc = make_float4(0.f, 0.f, 0.f, 0.f);
    int e = start;
    for (; e + 1 < end; e += 2) {
        int2 p0 = pairs[e];
        int2 p1 = pairs[e + 1];
        float v0 = __int_as_float(p0.y);
        float v1 = __int_as_float(p1.y);
        float4 t0 = ((const float4*)(embeds + (size_t)p0.x * D_FEAT))[lane];
        float4 t1 = ((const float4*)(embeds + (size_t)p1.x * D_FEAT))[lane];
        acc.x += v0 * t0.x; acc.y += v0 * t0.y; acc.z += v0 * t0.z; acc.w += v0 * t0.w;
        acc.x += v1 * t1.x; acc.y += v1 * t1.y; acc.z += v1 * t1.z; acc.w += v1 * t1.w;
    }
    if (e < end) {
        int2 p = pairs[e];
        float v = __int_as_float(p.y);
        float4 t = ((const float4*)(embeds + (size_t)p.x * D_FEAT))[lane];
        acc.x += v * t.x; acc.y += v * t.y; acc.z += v * t.z; acc.w += v * t.w;
    }
    ((float4*)(out + (size_t)row * D_FEAT))[lane] = acc;
}

extern "C" void kernel_launch(void* const* d_in, const int* in_sizes, int n_in,
                              void* d_out, int out_size, void* d_ws, size_t ws_size,
                              hipStream_t stream) {
    const int*   rows   = (const int*)d_in[0];
    const int*   cols   = (const int*)d_in[1];
    const float* vals   = (const float*)d_in[2];
    const float* embeds = (const float*)d_in[3];
    float*       out    = (float*)d_out;

    const int n_edges = in_sizes[0];
    const int n_rows  = out_size / D_FEAT;

    // workspace layout
    size_t counts_b  = (size_t)n_rows * sizeof(int);
    size_t offsets_b = (size_t)(n_rows + 1) * sizeof(int);
    size_t cursor_b  = (size_t)n_rows * sizeof(int);
    size_t pairs_b   = (size_t)n_edges * sizeof(int2);
    size_t need = counts_b + offsets_b + cursor_b + pairs_b;

    if (ws_size < need) {
        // fallback: atomic scatter
        int out_n4 = out_size / 4;
        zero_out_kernel<<<(out_n4 + 255) / 256, 256, 0, stream>>>(out, out_n4);
        long long total = (long long)n_edges * 32;
        int grid = (int)((total + 255) / 256);
        coo_scatter_atomic_kernel<<<grid, 256, 0, stream>>>(rows, cols, vals, embeds, out, n_edges);
        return;
    }

    char* ws = (char*)d_ws;
    int*  counts  = (int*)ws;                 ws += counts_b;
    int*  offsets = (int*)ws;                 ws += offsets_b;
    int*  cursor  = (int*)ws;                 ws += cursor_b;
    int2* pairs   = (int2*)ws;

    hipMemsetAsync(counts, 0, counts_b, stream);

    hist_kernel<<<(n_edges + 255) / 256, 256, 0, stream>>>(rows, counts, n_edges);
    scan_kernel<<<1, SCAN_THREADS, 0, stream>>>(counts, offsets, cursor, n_rows, n_edges);
    scatter_pairs_kernel<<<(n_edges + 255) / 256, 256, 0, stream>>>(rows, cols, vals, cursor, pairs, n_edges);

    int grid = (n_rows + 3) / 4;   // 4 rows per 128-thread block
    reduce_kernel<<<grid, 128, 0, stream>>>(offsets, pairs, embeds, out, n_rows);
}

// Round 3
// 521.168 us; speedup vs baseline: 10.4169x; 1.7507x over previous
//
#include <hip/hip_runtime.h>

#define D_FEAT 128

// ---------- fallback path (round-1 atomic scatter) ----------
__global__ void zero_out_kernel(float* __restrict__ out, int n4) {
    int i = blockIdx.x * blockDim.x + threadIdx.x;
    if (i < n4) ((float4*)out)[i] = make_float4(0.f, 0.f, 0.f, 0.f);
}

__global__ void coo_scatter_atomic_kernel(const int* __restrict__ rows,
                                          const int* __restrict__ cols,
                                          const float* __restrict__ vals,
                                          const float* __restrict__ embeds,
                                          float* __restrict__ out,
                                          int n_edges) {
    int tid  = blockIdx.x * blockDim.x + threadIdx.x;
    int edge = tid >> 5;
    int lane = tid & 31;
    if (edge >= n_edges) return;
    int   r = rows[edge];
    int   c = cols[edge];
    float v = vals[edge];
    const float4* src = (const float4*)(embeds + (size_t)c * D_FEAT);
    float4 e = src[lane];
    float* dst = out + (size_t)r * D_FEAT + lane * 4;
    atomicAdd(dst + 0, v * e.x);
    atomicAdd(dst + 1, v * e.y);
    atomicAdd(dst + 2, v * e.z);
    atomicAdd(dst + 3, v * e.w);
}

// ---------- linked-list path ----------

// Per edge: push onto row's list. head[] random 4B atomics into a 400 KB
// L2-resident array; node[] write is fully coalesced (indexed by edge id).
__global__ void link_kernel(const int* __restrict__ rows,
                            const int* __restrict__ cols,
                            const float* __restrict__ vals,
                            int* __restrict__ head,
                            int4* __restrict__ node,
                            int n_edges) {
    int i = blockIdx.x * blockDim.x + threadIdx.x;
    if (i >= n_edges) return;
    int   r = rows[i];
    int   c = cols[i];
    float v = vals[i];
    int prev = atomicExch(&head[r], i);
    node[i] = make_int4(prev, c, __float_as_int(v), 0);
}

// 256 threads/block = 8 groups of 32 lanes; each group reduces one row by
// chasing its linked list. Lane l owns dims [4l, 4l+4).
// Software-pipelined: next-node load and current embed gather issue together.
__global__ void reduce_chase_kernel(const int* __restrict__ head,
                                    const int4* __restrict__ node,
                                    const float* __restrict__ embeds,
                                    float* __restrict__ out,
                                    int n_rows) {
    int g    = threadIdx.x >> 5;
    int lane = threadIdx.x & 31;
    int row  = blockIdx.x * 8 + g;
    if (row >= n_rows) return;

    float4 acc = make_float4(0.f, 0.f, 0.f, 0.f);
    int e = head[row];
    if (e >= 0) {
        int4 nd = node[e];
        while (nd.x >= 0) {
            int4 nd_next = node[nd.x];   // issue chain load early
            const float4* src = (const float4*)(embeds + (size_t)nd.y * D_FEAT);
            float4 t = src[lane];        // overlaps with nd_next load
            float  v = __int_as_float(nd.z);
            acc.x += v * t.x; acc.y += v * t.y; acc.z += v * t.z; acc.w += v * t.w;
            nd = nd_next;
        }
        // tail node
        const float4* src = (const float4*)(embeds + (size_t)nd.y * D_FEAT);
        float4 t = src[lane];
        float  v = __int_as_float(nd.z);
        acc.x += v * t.x; acc.y += v * t.y; acc.z += v * t.z; acc.w += v * t.w;
    }
    ((float4*)(out + (size_t)row * D_FEAT))[lane] = acc;
}

extern "C" void kernel_launch(void* const* d_in, const int* in_sizes, int n_in,
                              void* d_out, int out_size, void* d_ws, size_t ws_size,
                              hipStream_t stream) {
    const int*   rows   = (const int*)d_in[0];
    const int*   cols   = (const int*)d_in[1];
    const float* vals   = (const float*)d_in[2];
    const float* embeds = (const float*)d_in[3];
    float*       out    = (float*)d_out;

    const int n_edges = in_sizes[0];
    const int n_rows  = out_size / D_FEAT;

    size_t head_b = ((size_t)n_rows * sizeof(int) + 255) & ~(size_t)255;
    size_t node_b = (size_t)n_edges * sizeof(int4);
    size_t need   = head_b + node_b;

    if (ws_size < need) {
        // fallback: atomic scatter
        int out_n4 = out_size / 4;
        zero_out_kernel<<<(out_n4 + 255) / 256, 256, 0, stream>>>(out, out_n4);
        long long total = (long long)n_edges * 32;
        int grid = (int)((total + 255) / 256);
        coo_scatter_atomic_kernel<<<grid, 256, 0, stream>>>(rows, cols, vals, embeds, out, n_edges);
        return;
    }

    char* ws   = (char*)d_ws;
    int*  hd   = (int*)ws;
    int4* node = (int4*)(ws + head_b);

    hipMemsetAsync(hd, 0xFF, (size_t)n_rows * sizeof(int), stream);  // head = -1

    link_kernel<<<(n_edges + 255) / 256, 256, 0, stream>>>(rows, cols, vals, hd, node, n_edges);

    int grid = (n_rows + 7) / 8;   // 8 rows per 256-thread block
    reduce_chase_kernel<<<grid, 256, 0, stream>>>(hd, node, embeds, out, n_rows);
}